// Round 3
// baseline (280.031 us; speedup 1.0000x reference)
//
#include <hip/hip_runtime.h>
#include <hip/hip_bf16.h>

// x[16,32,32,32,32] f32, w[32,64,3,3,3] f32, b[64] f32
// ConvTranspose3d(s=2,p=1,k=3) -> (+bias)*0.5 -> maxpool2 -> mean -> clamp[0,1] -> out[16,64]
//
// Window algebra (validated R0/R1): window w covers conv outputs {2w,2w+1}/dim,
// inputs {w,w+1}/dim; per-dim (delta,k,parity): (0,1,0) (0,2,1) (1,0,1). No bounds checks.
// MFMA 16x16x32 bf16: M=16 windows(ww), N=16 co, K=32=Cin (layouts verified in R1, absmax 2e-3).
//
// R2 structure: block = (b, wd, whg of 8 wh-windows); LDS tile [dd2][hh9][w32][ci32] bf16
// (36 KB); window-PAIR processing reuses the shared middle h-row: 12 A-frags / 54 MFMA.
// Fully unrolled pair loop -> ds_read offsets are immediates.
//
// ws: [0,4096)B accS[16][64] f32; [4096,...) wB bf16 [tap27][cotile4][lane64][j8]

typedef __bf16 bf16x8 __attribute__((ext_vector_type(8)));
typedef float  f32x4  __attribute__((ext_vector_type(4)));
typedef unsigned short ushort_t;
typedef ushort_t ushort8 __attribute__((ext_vector_type(8)));

#define NWIN 29791  // 31^3

__device__ inline ushort_t f2bf(float f) {
    unsigned u = __builtin_bit_cast(unsigned, f);
    u += 0x7FFFu + ((u >> 16) & 1u);   // RNE
    return (ushort_t)(u >> 16);
}

__global__ __launch_bounds__(256) void prep_kernel(const float* __restrict__ w,
                                                   float* __restrict__ ws) {
    int idx = blockIdx.x * 256 + threadIdx.x;
    if (idx < 1024) ws[idx] = 0.f;
    if (idx < 55296) {
        ushort_t* wB = (ushort_t*)((char*)ws + 4096);
        int t = idx >> 11;          // tap [0,27)
        int c = (idx >> 9) & 3;     // co tile
        int l = (idx >> 3) & 63;    // lane
        int j = idx & 7;
        int ci = ((l >> 4) << 3) + j;
        int co = (c << 4) + (l & 15);
        wB[idx] = f2bf(w[(ci * 64 + co) * 27 + t]);
    }
}

// grid = 16 b * 31 wd * 4 whg, 256 threads
__global__ __launch_bounds__(256, 2) void main_kernel(const float* __restrict__ x,
                                                      const float* __restrict__ ws_ro,
                                                      float* __restrict__ accS) {
    __shared__ ushort_t xT[18432];  // [dd2][hh9][w32][ci32] bf16, swizzle s=kq^(w&3)^((w>>2)&3)

    int bid = blockIdx.x;
    int b   = bid / 124;            // 31*4
    int r   = bid - b * 124;
    int wd  = r >> 2;               // [0,31)
    int whg = r & 3;                // wh group of 8
    int tid = threadIdx.x;
    int lane = tid & 63;
    int wave = tid >> 6;

    // ---- this wave's 27 weight B-frags -> registers (AGPR-eligible)
    const bf16x8* wBv = (const bf16x8*)((const char*)ws_ro + 4096);
    bf16x8 Bf[27];
#pragma unroll
    for (int t = 0; t < 27; ++t) Bf[t] = wBv[(t * 4 + wave) * 64 + lane];

    // ---- stage x tile: d in {wd,wd+1}, h in [8whg, 8whg+9) (clamped), all w, all ci
    const float* xb = x + (size_t)b * (32u * 32768u);
#pragma unroll
    for (int it = 0; it < 9; ++it) {
        int c  = tid + (it << 8);       // [0,2304) ushort8 chunks
        int w  = c & 31;
        int kq = (c >> 5) & 3;
        int hq = c >> 7;                // [0,18)
        int hh = hq % 9;
        int dd = hq / 9;
        int h  = (whg << 3) + hh; if (h > 31) h = 31;  // clamped row used only by skipped window
        const float* src = xb + (size_t)(kq * 8) * 32768u
                              + (size_t)((((wd + dd) << 5) + h) << 5) + w;
        float v[8];
#pragma unroll
        for (int i = 0; i < 8; ++i) v[i] = src[(size_t)i * 32768u];
        ushort8 pk;
#pragma unroll
        for (int i = 0; i < 4; ++i) {
            __hip_bfloat162 p2 = __float22bfloat162_rn(float2{v[2 * i], v[2 * i + 1]});
            pk[2 * i]     = __builtin_bit_cast(ushort_t, p2.x);
            pk[2 * i + 1] = __builtin_bit_cast(ushort_t, p2.y);
        }
        int s = kq ^ (w & 3) ^ ((w >> 2) & 3);
        *(ushort8*)&xT[(((dd * 9 + hh) << 5) + w) * 32 + (s << 3)] = pk;
    }
    __syncthreads();

    int m  = lane & 15;
    int kq = lane >> 4;
    float runsum = 0.f;

#pragma unroll 1
    for (int half = 0; half < 2; ++half) {
        int wbase = half << 4;
        int w0 = wbase + m;                    // <= 31 always
        int w1 = w0 + 1; if (w1 > 31) w1 = 31; // clamped lane masked in epilogue
        int col0 = (w0 << 5) + ((kq ^ (w0 & 3) ^ ((w0 >> 2) & 3)) << 3);
        int col1 = (w1 << 5) + ((kq ^ (w1 & 3) ^ ((w1 >> 2) & 3)) << 3);

#pragma unroll
        for (int p = 0; p < 4; ++p) {
            // windows wh0 = 8*whg + 2p (always valid), wh1 = wh0+1 (invalid only whg=3,p=3)
            bool two = (whg < 3) || (p < 3);   // block-uniform

            // 12 A-frags: h rows hl..hl+2, dd 0/1, dw 0/1 (offsets fold to immediates)
            bf16x8 F[2][3][2];
#pragma unroll
            for (int dd = 0; dd < 2; ++dd)
#pragma unroll
                for (int hi = 0; hi < 3; ++hi) {
                    int row = (dd * 9 + 2 * p + hi) << 10;  // ushort index of row base
                    F[dd][hi][0] = *(const bf16x8*)&xT[row + col0];
                    F[dd][hi][1] = *(const bf16x8*)&xT[row + col1];
                }

            // two windows sharing the middle h row
#pragma unroll
            for (int win = 0; win < 2; ++win) {
                if (win == 1 && !two) break;
                f32x4 C[8];
#pragma unroll
                for (int e = 0; e < 8; ++e) C[e] = (f32x4){0.f, 0.f, 0.f, 0.f};
#pragma unroll
                for (int kd = 0; kd < 3; ++kd) {
                    const int dd = (kd == 0) ? 1 : 0, ed = (kd == 1) ? 0 : 1;
#pragma unroll
                    for (int kh = 0; kh < 3; ++kh) {
                        const int dh = (kh == 0) ? 1 : 0, eh = (kh == 1) ? 0 : 1;
#pragma unroll
                        for (int kw = 0; kw < 3; ++kw) {
                            const int dw = (kw == 0) ? 1 : 0, ew = (kw == 1) ? 0 : 1;
                            C[ed * 4 + eh * 2 + ew] = __builtin_amdgcn_mfma_f32_16x16x32_bf16(
                                F[dd][win + dh][dw], Bf[kd * 9 + kh * 3 + kw],
                                C[ed * 4 + eh * 2 + ew], 0, 0, 0);
                        }
                    }
                }
                // max over 8 parities, masked row-sum
                f32x4 mx = C[0];
#pragma unroll
                for (int e = 1; e < 8; ++e)
#pragma unroll
                    for (int q = 0; q < 4; ++q) mx[q] = fmaxf(mx[q], C[e][q]);
#pragma unroll
                for (int rr = 0; rr < 4; ++rr) {
                    int ww = wbase + (kq << 2) + rr;
                    if (ww < 31) runsum += mx[rr];
                }
            }
        }
    }

    // lanes with same n=(lane&15) hold partials for the same co
    runsum += __shfl_xor(runsum, 16, 64);
    runsum += __shfl_xor(runsum, 32, 64);
    if (lane < 16) atomicAdd(&accS[(b << 6) + (wave << 4) + lane], runsum);
}

__global__ __launch_bounds__(256) void finalize_kernel(const float* __restrict__ accS,
                                                       const float* __restrict__ bias,
                                                       float* __restrict__ out) {
    int i = blockIdx.x * 256 + threadIdx.x;
    if (i < 1024) {
        int co = i & 63;
        float v = (accS[i] * (1.f / (float)NWIN) + bias[co]) * 0.5f;
        v = fminf(fmaxf(v, 0.f), 1.f);
        out[i] = v;
    }
}

extern "C" void kernel_launch(void* const* d_in, const int* in_sizes, int n_in,
                              void* d_out, int out_size, void* d_ws, size_t ws_size,
                              hipStream_t stream) {
    const float* x    = (const float*)d_in[0];
    const float* w    = (const float*)d_in[1];
    const float* bias = (const float*)d_in[2];
    float* out = (float*)d_out;
    float* ws  = (float*)d_ws;

    prep_kernel<<<216, 256, 0, stream>>>(w, ws);
    main_kernel<<<16 * 31 * 4, 256, 0, stream>>>(x, ws, ws);
    finalize_kernel<<<4, 256, 0, stream>>>(ws, bias, out);
}

// Round 4
// 132.679 us; speedup vs baseline: 2.1106x; 2.1106x over previous
//
#include <hip/hip_runtime.h>
#include <hip/hip_bf16.h>

// x[16,32,32,32,32] f32, w[32,64,3,3,3] f32, b[64] f32
// ConvTranspose3d(s=2,p=1,k=3) -> (+bias)*0.5 -> maxpool2 -> mean -> clamp[0,1] -> out[16,64]
//
// Window algebra (validated R0/R1): window w covers conv outputs {2w,2w+1}/dim,
// inputs {w,w+1}/dim; per-dim (delta,k,parity): (0,1,0) (0,2,1) (1,0,1). No bounds checks.
// MFMA 16x16x32 bf16: M=16 windows(ww), N=16 co, K=32=Cin (layouts verified R1, absmax 2e-3).
//
// R4: h-pairing (12 A-frags per 54 MFMAs) with FULLY STATIC indexing (R3 spilled to scratch
// because a data-dependent break kept `win` dynamic -> F[] in scratch, 151 MB of spill).
// Tap order statically scheduled for same-C distance >=3 to kill MFMA accumulate stalls.
//
// ws: [0,4096)B accS[16][64] f32; [4096,...) wB bf16 [tap27][cotile4][lane64][j8]

typedef __bf16 bf16x8 __attribute__((ext_vector_type(8)));
typedef float  f32x4  __attribute__((ext_vector_type(4)));
typedef unsigned short ushort_t;
typedef ushort_t ushort8 __attribute__((ext_vector_type(8)));

#define NWIN 29791  // 31^3

__device__ inline ushort_t f2bf(float f) {
    unsigned u = __builtin_bit_cast(unsigned, f);
    u += 0x7FFFu + ((u >> 16) & 1u);   // RNE
    return (ushort_t)(u >> 16);
}

__global__ __launch_bounds__(256) void prep_kernel(const float* __restrict__ w,
                                                   float* __restrict__ ws) {
    int idx = blockIdx.x * 256 + threadIdx.x;
    if (idx < 1024) ws[idx] = 0.f;
    if (idx < 55296) {
        ushort_t* wB = (ushort_t*)((char*)ws + 4096);
        int t = idx >> 11;          // tap [0,27)
        int c = (idx >> 9) & 3;     // co tile
        int l = (idx >> 3) & 63;    // lane
        int j = idx & 7;
        int ci = ((l >> 4) << 3) + j;
        int co = (c << 4) + (l & 15);
        wB[idx] = f2bf(w[(ci * 64 + co) * 27 + t]);
    }
}

// Static tap schedule: same-C minimum distance 3 (C = parity triple e=(k!=1) per dim).
__device__ __constant__ const int SEQ[27][3] = {
    {0,0,0},{1,0,0},{0,1,0},{0,0,1},
    {0,0,2},{1,1,0},{1,0,1},{0,1,1},
    {0,2,0},{1,0,2},{0,1,2},{0,2,1},
    {0,2,2},{1,1,2},{1,2,1},{1,1,1},
    {2,0,0},{1,2,0},{2,1,0},{2,0,1},
    {2,0,2},{2,1,1},{1,2,2},{2,2,0},
    {2,1,2},{2,2,1},{2,2,2}
};

// grid = 16 b * 31 wd * 4 whg, 256 threads
__global__ __launch_bounds__(256, 2) void main_kernel(const float* __restrict__ x,
                                                      const float* __restrict__ ws_ro,
                                                      float* __restrict__ accS) {
    __shared__ ushort_t xT[18432];  // [dd2][hh9][w32][ci32] bf16, swizzle s=kq^(w&3)^((w>>2)&3)

    int bid = blockIdx.x;
    int b   = bid / 124;            // 31*4
    int r   = bid - b * 124;
    int wd  = r >> 2;               // [0,31)
    int whg = r & 3;                // wh group of 8
    int tid = threadIdx.x;
    int lane = tid & 63;
    int wave = tid >> 6;

    // ---- this wave's 27 weight B-frags -> registers (AGPR side of unified file)
    const bf16x8* wBv = (const bf16x8*)((const char*)ws_ro + 4096);
    bf16x8 Bf[27];
#pragma unroll
    for (int t = 0; t < 27; ++t) Bf[t] = wBv[(t * 4 + wave) * 64 + lane];

    // ---- stage x tile: d in {wd,wd+1}, h in [8whg, 8whg+9) (clamped), all w, all ci
    const float* xb = x + (size_t)b * (32u * 32768u);
#pragma unroll
    for (int it = 0; it < 9; ++it) {
        int c  = tid + (it << 8);       // [0,2304) ushort8 chunks
        int w  = c & 31;
        int kq = (c >> 5) & 3;
        int hq = c >> 7;                // [0,18)
        int hh = hq % 9;
        int dd = hq / 9;
        int h  = (whg << 3) + hh; if (h > 31) h = 31;  // clamped rows only feed masked windows
        const float* src = xb + (size_t)(kq * 8) * 32768u
                              + (size_t)((((wd + dd) << 5) + h) << 5) + w;
        float v[8];
#pragma unroll
        for (int i = 0; i < 8; ++i) v[i] = src[(size_t)i * 32768u];
        ushort8 pk;
#pragma unroll
        for (int i = 0; i < 4; ++i) {
            __hip_bfloat162 p2 = __float22bfloat162_rn(float2{v[2 * i], v[2 * i + 1]});
            pk[2 * i]     = __builtin_bit_cast(ushort_t, p2.x);
            pk[2 * i + 1] = __builtin_bit_cast(ushort_t, p2.y);
        }
        int s = kq ^ (w & 3) ^ ((w >> 2) & 3);
        *(ushort8*)&xT[(((dd * 9 + hh) << 5) + w) * 32 + (s << 3)] = pk;
    }
    __syncthreads();

    int m  = lane & 15;
    int kq = lane >> 4;
    float runsum = 0.f;

#pragma unroll 1
    for (int half = 0; half < 2; ++half) {
        int wbase = half << 4;
        int w0 = wbase + m;                    // <= 31 always
        int w1 = w0 + 1; if (w1 > 31) w1 = 31; // clamped lane masked in epilogue
        int col0 = (w0 << 5) + ((kq ^ (w0 & 3) ^ ((w0 >> 2) & 3)) << 3);
        int col1 = (w1 << 5) + ((kq ^ (w1 & 3) ^ ((w1 >> 2) & 3)) << 3);

#pragma unroll 1
        for (int p = 0; p < 4; ++p) {
            // 12 A-frags: h rows 2p..2p+2, dd 0/1, dw 0/1 (row offsets are immediates)
            bf16x8 F[2][3][2];
#pragma unroll
            for (int dd = 0; dd < 2; ++dd)
#pragma unroll
                for (int hi = 0; hi < 3; ++hi) {
                    int row = (dd * 9 + 2 * p + hi) << 10;  // ushort index of row base
                    F[dd][hi][0] = *(const bf16x8*)&xT[row + col0];
                    F[dd][hi][1] = *(const bf16x8*)&xT[row + col1];
                }

            // two windows sharing the middle h row — FULLY unrolled, no break
#pragma unroll
            for (int win = 0; win < 2; ++win) {
                f32x4 C[8];
#pragma unroll
                for (int e = 0; e < 8; ++e) C[e] = (f32x4){0.f, 0.f, 0.f, 0.f};
#pragma unroll
                for (int t = 0; t < 27; ++t) {
                    const int kd = SEQ[t][0], kh = SEQ[t][1], kw = SEQ[t][2];
                    const int dd = (kd == 0) ? 1 : 0, ed = (kd == 1) ? 0 : 1;
                    const int dh = (kh == 0) ? 1 : 0, eh = (kh == 1) ? 0 : 1;
                    const int dw = (kw == 0) ? 1 : 0, ew = (kw == 1) ? 0 : 1;
                    C[ed * 4 + eh * 2 + ew] = __builtin_amdgcn_mfma_f32_16x16x32_bf16(
                        F[dd][win + dh][dw], Bf[kd * 9 + kh * 3 + kw],
                        C[ed * 4 + eh * 2 + ew], 0, 0, 0);
                }
                // max over 8 parities, masked row-sum
                int wh = (whg << 3) + 2 * p + win;
                f32x4 mx = C[0];
#pragma unroll
                for (int e = 1; e < 8; ++e)
#pragma unroll
                    for (int q = 0; q < 4; ++q) mx[q] = fmaxf(mx[q], C[e][q]);
                if (wh < 31) {
#pragma unroll
                    for (int rr = 0; rr < 4; ++rr) {
                        int ww = wbase + (kq << 2) + rr;
                        if (ww < 31) runsum += mx[rr];
                    }
                }
            }
        }
    }

    // lanes with same n=(lane&15) hold partials for the same co
    runsum += __shfl_xor(runsum, 16, 64);
    runsum += __shfl_xor(runsum, 32, 64);
    if (lane < 16) atomicAdd(&accS[(b << 6) + (wave << 4) + lane], runsum);
}

__global__ __launch_bounds__(256) void finalize_kernel(const float* __restrict__ accS,
                                                       const float* __restrict__ bias,
                                                       float* __restrict__ out) {
    int i = blockIdx.x * 256 + threadIdx.x;
    if (i < 1024) {
        int co = i & 63;
        float v = (accS[i] * (1.f / (float)NWIN) + bias[co]) * 0.5f;
        v = fminf(fmaxf(v, 0.f), 1.f);
        out[i] = v;
    }
}

extern "C" void kernel_launch(void* const* d_in, const int* in_sizes, int n_in,
                              void* d_out, int out_size, void* d_ws, size_t ws_size,
                              hipStream_t stream) {
    const float* x    = (const float*)d_in[0];
    const float* w    = (const float*)d_in[1];
    const float* bias = (const float*)d_in[2];
    float* out = (float*)d_out;
    float* ws  = (float*)d_ws;

    prep_kernel<<<216, 256, 0, stream>>>(w, ws);
    main_kernel<<<16 * 31 * 4, 256, 0, stream>>>(x, ws, ws);
    finalize_kernel<<<4, 256, 0, stream>>>(ws, bias, out);
}

// Round 5
// 131.325 us; speedup vs baseline: 2.1324x; 1.0103x over previous
//
#include <hip/hip_runtime.h>
#include <hip/hip_bf16.h>

// x[16,32,32,32,32] f32, w[32,64,3,3,3] f32, b[64] f32
// ConvTranspose3d(s=2,p=1,k=3) -> (+bias)*0.5 -> maxpool2 -> mean -> clamp[0,1] -> out[16,64]
//
// Window algebra (validated R0/R1): window w covers conv outputs {2w,2w+1}/dim,
// inputs {w,w+1}/dim; per-dim (delta,k,parity): (0,1,0) (0,2,1) (1,0,1). No bounds checks.
// MFMA 16x16x32 bf16: M=16 windows(ww), N=16 co, K=32=Cin (layouts verified R1, absmax 2e-3).
//
// R5: VALU-diet on the R4 structure (2 waves/SIMD is reg-capped; VALU pipe was ~30% busy
// with compiler bloat): (1) first-tap-zero C operand (kills 512 accvgpr zero-inits/wave),
// (2) wave-uniform staging: wave stages its 8 ci planes, SGPR base + immediate offsets,
// (3) max3-shaped epilogue. LDS tile [dd2][hh9][w32][ci32] bf16, swizzle s=kq^(w&3)^((w>>2)&3).
//
// ws: [0,4096)B accS[16][64] f32; [4096,...) wB bf16 [cotile4][tap27][lane64][j8]

typedef __bf16 bf16x8 __attribute__((ext_vector_type(8)));
typedef float  f32x4  __attribute__((ext_vector_type(4)));
typedef unsigned short ushort_t;
typedef ushort_t ushort8 __attribute__((ext_vector_type(8)));

#define NWIN 29791  // 31^3

__device__ inline ushort_t f2bf(float f) {
    unsigned u = __builtin_bit_cast(unsigned, f);
    u += 0x7FFFu + ((u >> 16) & 1u);   // RNE
    return (ushort_t)(u >> 16);
}

__global__ __launch_bounds__(256) void prep_kernel(const float* __restrict__ w,
                                                   float* __restrict__ ws) {
    int idx = blockIdx.x * 256 + threadIdx.x;
    if (idx < 1024) ws[idx] = 0.f;
    if (idx < 55296) {
        ushort_t* wB = (ushort_t*)((char*)ws + 4096);
        int j = idx & 7;
        int l = (idx >> 3) & 63;
        int q = idx >> 9;           // [0,108) = c*27+t
        int t = q % 27;
        int c = q / 27;
        int ci = ((l >> 4) << 3) + j;
        int co = (c << 4) + (l & 15);
        wB[idx] = f2bf(w[(ci * 64 + co) * 27 + t]);
    }
}

// Static tap schedule: same-C min distance 3. Fields: kd,kh,kw.
__device__ __constant__ const int SEQ[27][3] = {
    {0,0,0},{1,0,0},{0,1,0},{0,0,1},
    {0,0,2},{1,1,0},{1,0,1},{0,1,1},
    {0,2,0},{1,0,2},{0,1,2},{0,2,1},
    {0,2,2},{1,1,2},{1,2,1},{1,1,1},
    {2,0,0},{1,2,0},{2,1,0},{2,0,1},
    {2,0,2},{2,1,1},{1,2,2},{2,2,0},
    {2,1,2},{2,2,1},{2,2,2}
};

// grid = 16 b * 31 wd * 4 whg, 256 threads
__global__ __launch_bounds__(256, 2) void main_kernel(const float* __restrict__ x,
                                                      const float* __restrict__ ws_ro,
                                                      float* __restrict__ accS) {
    __shared__ ushort_t xT[18432];  // [dd2][hh9][w32][ci32] bf16

    int bid = blockIdx.x;
    int b   = bid / 124;            // 31*4
    int r   = bid - b * 124;
    int wd  = r >> 2;               // [0,31)
    int whg = r & 3;                // wh group of 8
    int tid = threadIdx.x;
    int lane = tid & 63;
    int wave = tid >> 6;
    int uw   = __builtin_amdgcn_readfirstlane(wave);  // wave-uniform -> SGPR addressing

    // ---- this wave's 27 weight B-frags -> registers (contiguous layout)
    const bf16x8* wBv = (const bf16x8*)((const char*)ws_ro + 4096);
    bf16x8 Bf[27];
#pragma unroll
    for (int t = 0; t < 27; ++t) Bf[t] = wBv[(uw * 27 + t) * 64 + lane];

    // ---- stage: wave uw stages ci planes [8uw, 8uw+8); lane = (dd = lane>>5, w = lane&31).
    // 9 row-iters; row r covers h = 8*whg + r (r=8 source-clamped when whg==3; dest row still 8).
    {
        int dd = lane >> 5;
        int wl = lane & 31;
        const float* xb = x + ((size_t)(b * 32 + uw * 8)) * 32768u
                            + ((size_t)(wd + 1) << 10) + ((size_t)(whg << 3) << 5);
        int voff = (dd - 1) * 1024 + wl;                  // element offset (>= -1024, valid: d=wd>=0)
        int ro8  = (whg == 3) ? 7 * 32 : 8 * 32;          // clamped last row source offset
        int s    = uw ^ (wl & 3) ^ ((wl >> 2) & 3);
        ushort_t* dst = &xT[((dd * 9) << 10) + (wl << 5) + (s << 3)];  // + r*1024 shorts per row
#pragma unroll
        for (int rr = 0; rr < 9; ++rr) {
            int ro = (rr < 8) ? rr * 32 : ro8;
            float v[8];
#pragma unroll
            for (int i = 0; i < 8; ++i) v[i] = xb[(size_t)i * 32768u + voff + ro];
            ushort8 pk;
#pragma unroll
            for (int i = 0; i < 4; ++i) {
                __hip_bfloat162 p2 = __float22bfloat162_rn(float2{v[2 * i], v[2 * i + 1]});
                pk[2 * i]     = __builtin_bit_cast(ushort_t, p2.x);
                pk[2 * i + 1] = __builtin_bit_cast(ushort_t, p2.y);
            }
            *(ushort8*)&dst[rr << 10] = pk;
        }
    }
    __syncthreads();

    int m  = lane & 15;
    int kq = lane >> 4;
    float runsum = 0.f;
    const f32x4 Z = (f32x4){0.f, 0.f, 0.f, 0.f};

#pragma unroll 1
    for (int half = 0; half < 2; ++half) {
        int wbase = half << 4;
        int w0 = wbase + m;                    // <= 31 always
        int w1 = w0 + 1; if (w1 > 31) w1 = 31; // clamped lane masked in epilogue
        int col0 = (w0 << 5) + ((kq ^ (w0 & 3) ^ ((w0 >> 2) & 3)) << 3);
        int col1 = (w1 << 5) + ((kq ^ (w1 & 3) ^ ((w1 >> 2) & 3)) << 3);

#pragma unroll 1
        for (int p = 0; p < 4; ++p) {
            // 12 A-frags: h rows 2p..2p+2, dd 0/1, dw 0/1 (row offsets are immediates)
            bf16x8 F[2][3][2];
#pragma unroll
            for (int dd = 0; dd < 2; ++dd)
#pragma unroll
                for (int hi = 0; hi < 3; ++hi) {
                    int row = (dd * 9 + 2 * p + hi) << 10;
                    F[dd][hi][0] = *(const bf16x8*)&xT[row + col0];
                    F[dd][hi][1] = *(const bf16x8*)&xT[row + col1];
                }

            // two windows sharing the middle h row — fully unrolled, no break
#pragma unroll
            for (int win = 0; win < 2; ++win) {
                f32x4 C[8];
#pragma unroll
                for (int t = 0; t < 27; ++t) {
                    const int kd = SEQ[t][0], kh = SEQ[t][1], kw = SEQ[t][2];
                    const int dd = (kd == 0) ? 1 : 0, ed = (kd == 1) ? 0 : 1;
                    const int dh = (kh == 0) ? 1 : 0, eh = (kh == 1) ? 0 : 1;
                    const int dw = (kw == 0) ? 1 : 0, ew = (kw == 1) ? 0 : 1;
                    const int ce = ed * 4 + eh * 2 + ew;
                    // first tap touching each parity class feeds Z (no C zero-init)
                    const bool first = (t == 0) | (t == 1) | (t == 2) | (t == 3) |
                                       (t == 5) | (t == 6) | (t == 7) | (t == 15);
                    C[ce] = __builtin_amdgcn_mfma_f32_16x16x32_bf16(
                        F[dd][win + dh][dw], Bf[kd * 9 + kh * 3 + kw],
                        first ? Z : C[ce], 0, 0, 0);
                }
                // max over 8 parities (max3-shaped tree), masked row-sum
                int wh = (whg << 3) + 2 * p + win;
                f32x4 mx;
#pragma unroll
                for (int q = 0; q < 4; ++q) {
                    float m1 = fmaxf(fmaxf(C[0][q], C[1][q]), C[2][q]);
                    float m2 = fmaxf(fmaxf(C[3][q], C[4][q]), C[5][q]);
                    float m3 = fmaxf(fmaxf(C[6][q], C[7][q]), m1);
                    mx[q] = fmaxf(m2, m3);
                }
                if (wh < 31) {
#pragma unroll
                    for (int rr = 0; rr < 4; ++rr) {
                        int ww = wbase + (kq << 2) + rr;
                        if (ww < 31) runsum += mx[rr];
                    }
                }
            }
        }
    }

    // lanes with same n=(lane&15) hold partials for the same co
    runsum += __shfl_xor(runsum, 16, 64);
    runsum += __shfl_xor(runsum, 32, 64);
    if (lane < 16) atomicAdd(&accS[(b << 6) + (wave << 4) + lane], runsum);
}

__global__ __launch_bounds__(256) void finalize_kernel(const float* __restrict__ accS,
                                                       const float* __restrict__ bias,
                                                       float* __restrict__ out) {
    int i = blockIdx.x * 256 + threadIdx.x;
    if (i < 1024) {
        int co = i & 63;
        float v = (accS[i] * (1.f / (float)NWIN) + bias[co]) * 0.5f;
        v = fminf(fmaxf(v, 0.f), 1.f);
        out[i] = v;
    }
}

extern "C" void kernel_launch(void* const* d_in, const int* in_sizes, int n_in,
                              void* d_out, int out_size, void* d_ws, size_t ws_size,
                              hipStream_t stream) {
    const float* x    = (const float*)d_in[0];
    const float* w    = (const float*)d_in[1];
    const float* bias = (const float*)d_in[2];
    float* out = (float*)d_out;
    float* ws  = (float*)d_ws;

    prep_kernel<<<216, 256, 0, stream>>>(w, ws);
    main_kernel<<<16 * 31 * 4, 256, 0, stream>>>(x, ws, ws);
    finalize_kernel<<<4, 256, 0, stream>>>(ws, bias, out);
}

// Round 6
// 129.627 us; speedup vs baseline: 2.1603x; 1.0131x over previous
//
#include <hip/hip_runtime.h>
#include <hip/hip_bf16.h>

// x[16,32,32,32,32] f32, w[32,64,3,3,3] f32, b[64] f32
// ConvTranspose3d(s=2,p=1,k=3) -> (+bias)*0.5 -> maxpool2 -> mean -> clamp[0,1] -> out[16,64]
//
// Window algebra (validated R0/R1): window w covers conv outputs {2w,2w+1}/dim,
// inputs {w,w+1}/dim; per-dim (delta,k,parity): (0,1,0) (0,2,1) (1,0,1). No bounds checks.
// MFMA 16x16x32 bf16: M=16 ww-windows, N=16 co, K=32=Cin (layouts verified R1).
//
// R6: occupancy push 2->3 waves/SIMD (512-reg pool, need <=170/wave):
//  - sequential parity-class groups: peak C live = 12 regs + mx 4 (was C[8]=32)
//  - single-window F[8] (32 regs, was 48)
//  - swizzle s = kq ^ ((w>>1)&3): A-reads exactly 2 lanes/bank-quad (free)
//  - __launch_bounds__(256,3)
// Class groups (per window, 27 MFMAs): A: (111)=kd2{4}+kd0{4} interleaved, mx=Ca+Cb;
// B: (011)kd1{4} / (101){4} interleaved; C: (110){4}/(001){2}/(010){2}; D: (100){2}/(000){1}.
//
// ws: [0,4096)B accS[16][64] f32; [4096,...) wB bf16 [cotile4][T27][lane64][j8],
// T in exact consumption order (see TAP tables).

typedef __bf16 bf16x8 __attribute__((ext_vector_type(8)));
typedef float  f32x4  __attribute__((ext_vector_type(4)));
typedef unsigned short ushort_t;
typedef ushort_t ushort8 __attribute__((ext_vector_type(8)));

#define NWIN 29791  // 31^3

__device__ inline ushort_t f2bf(float f) {
    unsigned u = __builtin_bit_cast(unsigned, f);
    u += 0x7FFFu + ((u >> 16) & 1u);   // RNE
    return (ushort_t)(u >> 16);
}

// Consumption-order tap list (kd,kh,kw) for T=0..26
__device__ __constant__ const unsigned char TKD[27] = {2,0,2,0,2,0,2,0, 1,0,1,2,1,0,1,2, 0,1,2,1,0,1,2,1, 0,1,2};
__device__ __constant__ const unsigned char TKH[27] = {0,0,0,0,2,2,2,2, 0,1,0,1,2,1,2,1, 0,1,0,0,2,1,2,2, 1,1,1};
__device__ __constant__ const unsigned char TKW[27] = {0,0,2,2,0,0,2,2, 0,0,2,0,0,2,2,2, 1,0,1,1,1,2,1,1, 1,1,1};

__global__ __launch_bounds__(256) void prep_kernel(const float* __restrict__ w,
                                                   float* __restrict__ ws) {
    int idx = blockIdx.x * 256 + threadIdx.x;
    if (idx < 1024) ws[idx] = 0.f;
    if (idx < 55296) {
        ushort_t* wB = (ushort_t*)((char*)ws + 4096);
        int j = idx & 7;
        int l = (idx >> 3) & 63;
        int q = idx >> 9;           // [0,108) = c*27+T
        int T = q % 27;
        int c = q / 27;
        int ci = ((l >> 4) << 3) + j;
        int co = (c << 4) + (l & 15);
        int k3 = TKD[T] * 9 + TKH[T] * 3 + TKW[T];
        wB[idx] = f2bf(w[(ci * 64 + co) * 27 + k3]);
    }
}

// grid = 16 b * 31 wd * 4 whg, 256 threads
__global__ __launch_bounds__(256, 3) void main_kernel(const float* __restrict__ x,
                                                      const float* __restrict__ ws_ro,
                                                      float* __restrict__ accS) {
    __shared__ ushort_t xT[18432];  // [dd2][hh9][w32][ci32] bf16, s = kq ^ ((w>>1)&3)

    int bid = blockIdx.x;
    int b   = bid / 124;            // 31*4
    int r   = bid - b * 124;
    int wd  = r >> 2;               // [0,31)
    int whg = r & 3;                // wh group of 8
    int tid = threadIdx.x;
    int lane = tid & 63;
    int wave = tid >> 6;
    int uw   = __builtin_amdgcn_readfirstlane(wave);

    // ---- this wave's 27 weight B-frags (consumption order) -> acc regs
    const bf16x8* wBv = (const bf16x8*)((const char*)ws_ro + 4096);
    bf16x8 Bf[27];
#pragma unroll
    for (int t = 0; t < 27; ++t) Bf[t] = wBv[(uw * 27 + t) * 64 + lane];

    // ---- stage: wave uw stages ci planes [8uw,8uw+8); lane = (dd=lane>>5, w=lane&31)
    {
        int dd = lane >> 5;
        int wl = lane & 31;
        const float* xb = x + ((size_t)(b * 32 + uw * 8)) * 32768u
                            + ((size_t)(wd + 1) << 10) + ((size_t)(whg << 3) << 5);
        int voff = (dd - 1) * 1024 + wl;
        int ro8  = (whg == 3) ? 7 * 32 : 8 * 32;          // clamped last row (masked window only)
        int s    = uw ^ ((wl >> 1) & 3);
        ushort_t* dst = &xT[((dd * 9) << 10) + (wl << 5) + (s << 3)];
#pragma unroll
        for (int rr = 0; rr < 9; ++rr) {
            int ro = (rr < 8) ? rr * 32 : ro8;
            float v[8];
#pragma unroll
            for (int i = 0; i < 8; ++i) v[i] = xb[(size_t)i * 32768u + voff + ro];
            ushort8 pk;
#pragma unroll
            for (int i = 0; i < 4; ++i) {
                __hip_bfloat162 p2 = __float22bfloat162_rn(float2{v[2 * i], v[2 * i + 1]});
                pk[2 * i]     = __builtin_bit_cast(ushort_t, p2.x);
                pk[2 * i + 1] = __builtin_bit_cast(ushort_t, p2.y);
            }
            *(ushort8*)&dst[rr << 10] = pk;
        }
    }
    __syncthreads();

    int m  = lane & 15;
    int kq = lane >> 4;
    float runsum = 0.f;
    const f32x4 Z = (f32x4){0.f, 0.f, 0.f, 0.f};

#pragma unroll 1
    for (int half = 0; half < 2; ++half) {
        int wbase = half << 4;
        int w0 = wbase + m;                    // <= 31
        int w1 = w0 + 1; if (w1 > 31) w1 = 31; // garbage -> window 31, masked
        int col0 = (w0 << 5) + ((kq ^ ((w0 >> 1) & 3)) << 3);
        int col1 = (w1 << 5) + ((kq ^ ((w1 >> 1) & 3)) << 3);

#pragma unroll
        for (int win = 0; win < 8; ++win) {
            // 8 A-frags: rows win, win+1; dd 0/1; dw 0/1 (all offsets immediate)
            bf16x8 F[2][2][2];
#pragma unroll
            for (int dd = 0; dd < 2; ++dd)
#pragma unroll
                for (int rr2 = 0; rr2 < 2; ++rr2) {
                    int row = (dd * 9 + win + rr2) << 10;
                    F[dd][rr2][0] = *(const bf16x8*)&xT[row + col0];
                    F[dd][rr2][1] = *(const bf16x8*)&xT[row + col1];
                }

            f32x4 mx;
            // ---- Block A: class (1,1,1) split by kd: Ca=kd2, Cb=kd0, (kh,kw) in {0,2}^2
            {
                f32x4 Ca, Cb;
                static constexpr int KHq[4] = {0, 0, 2, 2};
                static constexpr int KWq[4] = {0, 2, 0, 2};
#pragma unroll
                for (int q = 0; q < 4; ++q) {
                    const int dh = (KHq[q] == 0), dw = (KWq[q] == 0);
                    Ca = __builtin_amdgcn_mfma_f32_16x16x32_bf16(F[0][dh][dw], Bf[2 * q],
                                                                 q == 0 ? Z : Ca, 0, 0, 0);
                    Cb = __builtin_amdgcn_mfma_f32_16x16x32_bf16(F[1][dh][dw], Bf[2 * q + 1],
                                                                 q == 0 ? Z : Cb, 0, 0, 0);
                }
#pragma unroll
                for (int i = 0; i < 4; ++i) mx[i] = Ca[i] + Cb[i];
            }
            // ---- Block B: Cc = class (0,1,1) [kd=1,(kh,kw) in {0,2}^2]; Cd = (1,0,1)
            {
                f32x4 Cc, Cd;
                static constexpr int KHq[4] = {0, 0, 2, 2};
                static constexpr int KWq[4] = {0, 2, 0, 2};
                static constexpr int KDd[4] = {0, 2, 0, 2};
                static constexpr int KWd[4] = {0, 0, 2, 2};
#pragma unroll
                for (int q = 0; q < 4; ++q) {
                    const int dh = (KHq[q] == 0), dw = (KWq[q] == 0);
                    Cc = __builtin_amdgcn_mfma_f32_16x16x32_bf16(F[0][dh][dw], Bf[8 + 2 * q],
                                                                 q == 0 ? Z : Cc, 0, 0, 0);
                    const int dd2 = (KDd[q] == 0), dw2 = (KWd[q] == 0);
                    Cd = __builtin_amdgcn_mfma_f32_16x16x32_bf16(F[dd2][0][dw2], Bf[9 + 2 * q],
                                                                 q == 0 ? Z : Cd, 0, 0, 0);
                }
#pragma unroll
                for (int i = 0; i < 4; ++i) mx[i] = fmaxf(fmaxf(mx[i], Cc[i]), Cd[i]);
            }
            // ---- Block C: Ce = (1,1,0) {4}; Cf = (0,0,1) {2}; Cg = (0,1,0) {2}
            {
                f32x4 Ce, Cf, Cg;
                static constexpr int KDe[4] = {0, 2, 0, 2};
                static constexpr int KHe[4] = {0, 0, 2, 2};
#pragma unroll
                for (int q = 0; q < 4; ++q) {
                    const int dd2 = (KDe[q] == 0), dh2 = (KHe[q] == 0);
                    Ce = __builtin_amdgcn_mfma_f32_16x16x32_bf16(F[dd2][dh2][0], Bf[16 + 2 * q],
                                                                 q == 0 ? Z : Ce, 0, 0, 0);
                    if (q == 0)      Cf = __builtin_amdgcn_mfma_f32_16x16x32_bf16(F[0][0][1], Bf[17], Z, 0, 0, 0);
                    else if (q == 1) Cg = __builtin_amdgcn_mfma_f32_16x16x32_bf16(F[0][1][0], Bf[19], Z, 0, 0, 0);
                    else if (q == 2) Cf = __builtin_amdgcn_mfma_f32_16x16x32_bf16(F[0][0][0], Bf[21], Cf, 0, 0, 0);
                    else             Cg = __builtin_amdgcn_mfma_f32_16x16x32_bf16(F[0][0][0], Bf[23], Cg, 0, 0, 0);
                }
#pragma unroll
                for (int i = 0; i < 4; ++i)
                    mx[i] = fmaxf(fmaxf(mx[i], Ce[i]), fmaxf(Cf[i], Cg[i]));
            }
            // ---- Block D: Ch = (1,0,0) {2}; Ci = (0,0,0) {1}
            {
                f32x4 Ch, Ci;
                Ch = __builtin_amdgcn_mfma_f32_16x16x32_bf16(F[1][0][0], Bf[24], Z, 0, 0, 0);
                Ci = __builtin_amdgcn_mfma_f32_16x16x32_bf16(F[0][0][0], Bf[25], Z, 0, 0, 0);
                Ch = __builtin_amdgcn_mfma_f32_16x16x32_bf16(F[0][0][0], Bf[26], Ch, 0, 0, 0);
#pragma unroll
                for (int i = 0; i < 4; ++i) mx[i] = fmaxf(mx[i], fmaxf(Ch[i], Ci[i]));
            }

            // masked accumulate: wh = 8*whg + win, rows ww = wbase + kq*4 + rr
            int wh = (whg << 3) + win;
            if (wh < 31) {
#pragma unroll
                for (int rr = 0; rr < 4; ++rr) {
                    int ww = wbase + (kq << 2) + rr;
                    if (ww < 31) runsum += mx[rr];
                }
            }
        }
    }

    // lanes with same n=(lane&15) hold partials for the same co
    runsum += __shfl_xor(runsum, 16, 64);
    runsum += __shfl_xor(runsum, 32, 64);
    if (lane < 16) atomicAdd(&accS[(b << 6) + (wave << 4) + lane], runsum);
}

__global__ __launch_bounds__(256) void finalize_kernel(const float* __restrict__ accS,
                                                       const float* __restrict__ bias,
                                                       float* __restrict__ out) {
    int i = blockIdx.x * 256 + threadIdx.x;
    if (i < 1024) {
        int co = i & 63;
        float v = (accS[i] * (1.f / (float)NWIN) + bias[co]) * 0.5f;
        v = fminf(fmaxf(v, 0.f), 1.f);
        out[i] = v;
    }
}

extern "C" void kernel_launch(void* const* d_in, const int* in_sizes, int n_in,
                              void* d_out, int out_size, void* d_ws, size_t ws_size,
                              hipStream_t stream) {
    const float* x    = (const float*)d_in[0];
    const float* w    = (const float*)d_in[1];
    const float* bias = (const float*)d_in[2];
    float* out = (float*)d_out;
    float* ws  = (float*)d_ws;

    prep_kernel<<<216, 256, 0, stream>>>(w, ws);
    main_kernel<<<16 * 31 * 4, 256, 0, stream>>>(x, ws, ws);
    finalize_kernel<<<4, 256, 0, stream>>>(ws, bias, out);
}